// Round 2
// baseline (87455.786 us; speedup 1.0000x reference)
//
#include <hip/hip_runtime.h>

// ---------------------------------------------------------------------------
// TacotronDecoder on MI355X — multi-launch (non-cooperative) version.
// Phases per step t:
//   k_alstm : aLSTM gates+zoneout  || mel/gate projections for step t-1
//   k_energy: dLSTM partial gates  || location-conv + attention energies
//   k_ctx   : softmax + context (+ aw/aws update, alignment output)
//   k_dfin  : dLSTM finish (ctx part) + zoneout
// Prenet is input-only -> computed in 64-step chunks (or all 800 if ws is big).
// All recurrent state transposed [feature][batch]; lane = batch; weight rows
// wave-uniform -> scalar weight streams.
// ---------------------------------------------------------------------------

#define DEV_INLINE __device__ __forceinline__

constexpr int TB = 800;

// ws float offsets (small layout, ~15 MB max incl. 64-step x ring)
constexpr size_t PMT_O = 0;          // [64][128][256]
constexpr size_t GDT_O = 2097152;    // [2048][64]
constexpr size_t ENG_O = 2228224;    // [64][256]
constexpr size_t WQT_O = 2244608;    // [512][128]
constexpr size_t AH_O  = 2310144;    // [2][512][64]
constexpr size_t AC_O  = 2375680;
constexpr size_t DH_O  = 2441216;
constexpr size_t DC_O  = 2506752;
constexpr size_t CTX_O = 2572288;
constexpr size_t AW_O  = 2637824;    // [2][64][256]
constexpr size_t AWS_O = 2670592;
constexpr size_t XB_O  = 2703360;    // x ring: CH*[256][64]

// out float offsets
constexpr size_t MEL_O  = 0;         // (B,T,80)
constexpr size_t GATE_O = 4096000;   // (B,T)
constexpr size_t ALG_O  = 4147200;   // (B,T,L)

DEV_INLINE float sigf(float x)     { return 1.0f / (1.0f + __expf(-x)); }
DEV_INLINE float tanhfast(float x) { float e = __expf(2.0f * x); return 1.0f - 2.0f / (e + 1.0f); }

// wave-RNN GEMM segment: lane=batch, weight rows wave-uniform.
// inT: [seglen][64]; W row-major [*, ldw]; global-K slice [ks,ke), segment
// covers [segk0, segk0+seglen).
template<int NO>
DEV_INLINE void gseg(float* __restrict__ acc,
                     const float* __restrict__ inT,
                     const float* __restrict__ W, const int ldw, const int wcol0,
                     const int* __restrict__ rows, const int segk0, const int seglen,
                     const int ks, const int ke, const int lane)
{
  const int a0 = ks > segk0 ? ks : segk0;
  const int a1 = (ke < segk0 + seglen) ? ke : (segk0 + seglen);
  if (a0 >= a1) return;
  const float* __restrict__ ip = inT + (size_t)(a0 - segk0) * 64 + lane;
  const int n = a1 - a0;
  const float* wp[NO];
#pragma unroll
  for (int j = 0; j < NO; ++j)
    wp[j] = W + (size_t)rows[j] * ldw + (wcol0 + (a0 - segk0));
  for (int k = 0; k < n; k += 4) {
    const float x0 = ip[(k + 0) * 64];
    const float x1 = ip[(k + 1) * 64];
    const float x2 = ip[(k + 2) * 64];
    const float x3 = ip[(k + 3) * 64];
#pragma unroll
    for (int j = 0; j < NO; ++j)
      acc[j] += x0 * wp[j][k] + x1 * wp[j][k + 1] + x2 * wp[j][k + 2] + x3 * wp[j][k + 3];
  }
}

// ---------------------------------------------------------------------------
__global__ __launch_bounds__(256) void init_kernel(const float* __restrict__ Wq,
                                                   float* __restrict__ ws)
{
  const int i = blockIdx.x * 256 + threadIdx.x;       // 65536 threads
  {
    const int k = i >> 7, a = i & 127;                // WqT[k][a] = Wq[a][k]
    ws[WQT_O + i] = Wq[a * 512 + k];
  }
  for (size_t idx = i; idx < 393216; idx += 65536)    // zero AH..AWS (both bufs)
    ws[AH_O + idx] = 0.0f;
}

// ---------------------------------------------------------------------------
// prenet for steps [t0, t0+grid): block j handles t = t0 + j, writes slot j.
// ---------------------------------------------------------------------------
__global__ __launch_bounds__(256) void prenet_kernel(const float* __restrict__ mels,
                                                     const float* __restrict__ Wp1,
                                                     const float* __restrict__ Wp2,
                                                     const float* __restrict__ Wp3,
                                                     float* __restrict__ xb, int t0)
{
  __shared__ float smem[16384];
  const int t = t0 + blockIdx.x;
  const int tid = threadIdx.x;
  const int lane = tid & 63;
  const int wv = __builtin_amdgcn_readfirstlane(tid >> 6);

  if (t == 0) {
    for (int i = tid; i < 5200; i += 256) smem[i] = 0.0f;
  } else {
    for (int i = tid; i < 5120; i += 256) {
      const int b = i / 80, k = i - b * 80;
      smem[k * 65 + b] = mels[((size_t)b * TB + (t - 1)) * 80 + k];
    }
  }
  __syncthreads();

  float va[8][8];
#pragma unroll
  for (int g = 0; g < 8; ++g) {                    // L1: K=80
    const int u0 = wv * 64 + g * 8;
    float acc[8] = {};
    for (int k = 0; k < 80; ++k) {
      const float x = smem[k * 65 + lane];
#pragma unroll
      for (int j = 0; j < 8; ++j) acc[j] += x * Wp1[(u0 + j) * 80 + k];
    }
#pragma unroll
    for (int j = 0; j < 8; ++j) va[g][j] = fmaxf(acc[j], 0.0f);
  }
  __syncthreads();
#pragma unroll
  for (int g = 0; g < 8; ++g)
#pragma unroll
    for (int j = 0; j < 8; ++j) smem[(wv * 64 + g * 8 + j) * 64 + lane] = va[g][j];
  __syncthreads();

#pragma unroll
  for (int g = 0; g < 8; ++g) {                    // L2: K=256
    const int u0 = wv * 64 + g * 8;
    float acc[8] = {};
    for (int k = 0; k < 256; ++k) {
      const float x = smem[k * 64 + lane];
#pragma unroll
      for (int j = 0; j < 8; ++j) acc[j] += x * Wp2[(u0 + j) * 256 + k];
    }
#pragma unroll
    for (int j = 0; j < 8; ++j) va[g][j] = fmaxf(acc[j], 0.0f);
  }
  __syncthreads();
#pragma unroll
  for (int g = 0; g < 8; ++g)
#pragma unroll
    for (int j = 0; j < 8; ++j) smem[(wv * 64 + g * 8 + j) * 64 + lane] = va[g][j];
  __syncthreads();

#pragma unroll
  for (int g = 0; g < 8; ++g) {                    // L3: K=256 -> xb
    const int u0 = wv * 64 + g * 8;
    float acc[8] = {};
    for (int k = 0; k < 256; ++k) {
      const float x = smem[k * 64 + lane];
#pragma unroll
      for (int j = 0; j < 8; ++j) acc[j] += x * Wp3[(u0 + j) * 256 + k];
    }
#pragma unroll
    for (int j = 0; j < 8; ++j)
      xb[((size_t)blockIdx.x * 256 + (u0 + j)) * 64 + lane] = fmaxf(acc[j], 0.0f);
  }
}

// ---------------------------------------------------------------------------
// processed_memory: pmT[b][a][l] = sum_k enc[b,l,k]*Wm[a,k]. 256 blocks.
// ---------------------------------------------------------------------------
__global__ __launch_bounds__(256) void pm_kernel(const float* __restrict__ enc,
                                                 const float* __restrict__ Wm,
                                                 float* __restrict__ pmT)
{
  __shared__ float encL[64 * 129];
  const int b = blockIdx.x >> 2;
  const int l0 = (blockIdx.x & 3) * 64;
  const int tid = threadIdx.x;
  const int lane = tid & 63;
  const int wv = __builtin_amdgcn_readfirstlane(tid >> 6);

  float acc[4][8];
#pragma unroll
  for (int ai = 0; ai < 4; ++ai)
#pragma unroll
    for (int j = 0; j < 8; ++j) acc[ai][j] = 0.0f;

  for (int kc = 0; kc < 4; ++kc) {
    __syncthreads();
    for (int i = tid; i < 64 * 128; i += 256) {
      const int l = i >> 7, k = i & 127;
      encL[l * 129 + k] = enc[((size_t)b * 256 + l0 + l) * 512 + kc * 128 + k];
    }
    __syncthreads();
#pragma unroll
    for (int ai = 0; ai < 4; ++ai) {
      const int agrp = (ai * 4 + wv) * 8;
      for (int k = 0; k < 128; ++k) {
        const float x = encL[lane * 129 + k];
#pragma unroll
        for (int j = 0; j < 8; ++j)
          acc[ai][j] += x * Wm[(size_t)(agrp + j) * 512 + kc * 128 + k];
      }
    }
  }
#pragma unroll
  for (int ai = 0; ai < 4; ++ai) {
    const int agrp = (ai * 4 + wv) * 8;
#pragma unroll
    for (int j = 0; j < 8; ++j)
      pmT[((size_t)b * 128 + agrp + j) * 256 + l0 + lane] = acc[ai][j];
  }
}

// ---------------------------------------------------------------------------
// k_alstm: blocks 0..255 aLSTM (if do_a); 256..275 mel, 276 gate (if do_m).
// ---------------------------------------------------------------------------
__global__ __launch_bounds__(256) void k_alstm(
    const float* __restrict__ xt,  const float* __restrict__ ctx_i,
    const float* __restrict__ ah_i, const float* __restrict__ ac_i,
    float* __restrict__ ah_o, float* __restrict__ ac_o,
    const float* __restrict__ dh_i,
    const float* __restrict__ aWih, const float* __restrict__ aWhh,
    const float* __restrict__ abih, const float* __restrict__ abhh,
    const float* __restrict__ Wout, const float* __restrict__ bout,
    const float* __restrict__ Wgate, const float* __restrict__ bgate,
    float* __restrict__ out, int t, int do_a, int do_m)
{
  __shared__ float sm[2048];
  const int tid = threadIdx.x;
  const int blk = blockIdx.x;
  const int lane = tid & 63;
  const int wv = __builtin_amdgcn_readfirstlane(tid >> 6);

  if (blk < 256) {
    if (!do_a) return;
    const int u0 = blk * 2;
    int rows[8];
#pragma unroll
    for (int j = 0; j < 8; ++j) rows[j] = u0 + (j >> 2) + 512 * (j & 3);
    float acc[8] = {};
    const int ks = wv * 320, ke = ks + 320;       // K = 256 + 512 + 512
    gseg<8>(acc, xt,    aWih, 768, 0,   rows, 0,   256, ks, ke, lane);
    gseg<8>(acc, ctx_i, aWih, 768, 256, rows, 256, 512, ks, ke, lane);
    gseg<8>(acc, ah_i,  aWhh, 512, 0,   rows, 768, 512, ks, ke, lane);
#pragma unroll
    for (int j = 0; j < 8; ++j) sm[(wv * 8 + j) * 64 + lane] = acc[j];
    __syncthreads();
    if (tid < 128) {
      const int m = tid & 63, uq = tid >> 6;
      const int u = u0 + uq;
      float g[4];
#pragma unroll
      for (int q = 0; q < 4; ++q) {
        const int j = uq * 4 + q;
        const int row = u + 512 * q;
        g[q] = sm[j * 64 + m] + sm[(8 + j) * 64 + m] + sm[(16 + j) * 64 + m] + sm[(24 + j) * 64 + m]
             + abih[row] + abhh[row];
      }
      const float co = ac_i[u * 64 + m], ho = ah_i[u * 64 + m];
      const float c2 = sigf(g[1]) * co + sigf(g[0]) * tanhfast(g[2]);
      const float h2 = sigf(g[3]) * tanhfast(c2);
      ah_o[u * 64 + m] = 0.1f * ho + 0.9f * h2;
      ac_o[u * 64 + m] = 0.1f * co + 0.9f * c2;
    }
  } else if (do_m && blk < 277) {
    if (blk < 276) {                              // mel: 20 blocks x 4 cols
      const int c0 = (blk - 256) * 4;
      int rows[4] = {c0, c0 + 1, c0 + 2, c0 + 3};
      float acc[4] = {};
      const int ks = wv * 256, ke = ks + 256;     // K = 1024
      gseg<4>(acc, dh_i,  Wout, 1024, 0,   rows, 0,   512, ks, ke, lane);
      gseg<4>(acc, ctx_i, Wout, 1024, 512, rows, 512, 512, ks, ke, lane);
#pragma unroll
      for (int j = 0; j < 4; ++j) sm[(wv * 4 + j) * 64 + lane] = acc[j];
      __syncthreads();
      {
        const int m = tid & 63, c = tid >> 6;
        const float val = sm[c * 64 + m] + sm[(4 + c) * 64 + m] + sm[(8 + c) * 64 + m] + sm[(12 + c) * 64 + m]
                        + bout[c0 + c];
        out[MEL_O + ((size_t)m * TB + (t - 1)) * 80 + c0 + c] = val;
      }
    } else {                                      // gate
      float acc[1] = {};
      int rows1[1] = {0};
      const int ks = wv * 256, ke = ks + 256;
      gseg<1>(acc, dh_i,  Wgate, 1024, 0,   rows1, 0,   512, ks, ke, lane);
      gseg<1>(acc, ctx_i, Wgate, 1024, 512, rows1, 512, 512, ks, ke, lane);
      sm[wv * 64 + lane] = acc[0];
      __syncthreads();
      if (tid < 64) {
        const float val = sm[tid] + sm[64 + tid] + sm[128 + tid] + sm[192 + tid] + bgate[0];
        out[GATE_O + (size_t)tid * TB + (t - 1)] = val;
      }
    }
  }
}

// ---------------------------------------------------------------------------
// k_energy: blocks 0..255 dLSTM partial gates; 256..511 attention energies.
// ---------------------------------------------------------------------------
__global__ __launch_bounds__(256) void k_energy(
    const float* __restrict__ ah2,  const float* __restrict__ dh_i,
    const float* __restrict__ aw_i, const float* __restrict__ aws_i,
    const float* __restrict__ pmT,  const float* __restrict__ wqT,
    float* __restrict__ gdT, float* __restrict__ eng,
    const float* __restrict__ dWih, const float* __restrict__ dWhh,
    const float* __restrict__ dbih, const float* __restrict__ dbhh,
    const float* __restrict__ Wconv, const float* __restrict__ Wloc,
    const float* __restrict__ v, const int* __restrict__ len)
{
  __shared__ float sm[3584];
  const int tid = threadIdx.x;
  const int blk = blockIdx.x;
  const int lane = tid & 63;
  const int wv = __builtin_amdgcn_readfirstlane(tid >> 6);

  if (blk < 256) {
    const int u0 = blk * 2;
    int rows[8];
#pragma unroll
    for (int j = 0; j < 8; ++j) rows[j] = u0 + (j >> 2) + 512 * (j & 3);
    float acc[8] = {};
    const int ks = wv * 256, ke = ks + 256;       // K = 1024 (ah2 | dh)
    gseg<8>(acc, ah2,  dWih, 1024, 0, rows, 0,   512, ks, ke, lane);
    gseg<8>(acc, dh_i, dWhh, 512,  0, rows, 512, 512, ks, ke, lane);
#pragma unroll
    for (int j = 0; j < 8; ++j) sm[(wv * 8 + j) * 64 + lane] = acc[j];
    __syncthreads();
    if (tid < 128) {
      const int m = tid & 63, uq = tid >> 6;
      const int u = u0 + uq;
#pragma unroll
      for (int q = 0; q < 4; ++q) {
        const int j = uq * 4 + q;
        const int row = u + 512 * q;
        gdT[(size_t)row * 64 + m] =
            sm[j * 64 + m] + sm[(8 + j) * 64 + m] + sm[(16 + j) * 64 + m] + sm[(24 + j) * 64 + m]
          + dbih[row] + dbhh[row];
      }
    }
  } else {
    const int eb = blk - 256;
    const int b = eb >> 2;
    const int l0 = (eb & 3) * 64;
    float* qL   = sm;            // 128
    float* a2L  = sm + 128;      // 512
    float* awL  = sm + 640;      // 288 (halo-padded: awL[15+l] = aw[l])
    float* awsL = sm + 928;      // 288
    float* locL = sm + 1216;     // 64*33
    float* pr   = sm + 3328;     // 256

    for (int k = tid; k < 512; k += 256) a2L[k] = ah2[(size_t)k * 64 + b];
    if (tid < 15) { awL[tid] = 0.0f; awsL[tid] = 0.0f; awL[271 + tid] = 0.0f; awsL[271 + tid] = 0.0f; }
    awL[15 + tid]  = aw_i[b * 256 + tid];
    awsL[15 + tid] = aws_i[b * 256 + tid];
    __syncthreads();
    {
      const int a = tid & 127, h = tid >> 7;      // q partial over half of K
      float qp = 0.0f;
      const float* wq = wqT + (size_t)(h * 256) * 128 + a;
      const float* xv = a2L + h * 256;
      for (int k = 0; k < 256; k += 4)
        qp += wq[(k + 0) * 128] * xv[k + 0] + wq[(k + 1) * 128] * xv[k + 1]
            + wq[(k + 2) * 128] * xv[k + 2] + wq[(k + 3) * 128] * xv[k + 3];
      locL[h * 128 + a] = qp;
    }
    __syncthreads();
    if (tid < 128) qL[tid] = locL[tid] + locL[128 + tid];
    __syncthreads();
    {
      float awv[31], awsv[31];
#pragma unroll
      for (int k = 0; k < 31; ++k) { awv[k] = awL[l0 + lane + k]; awsv[k] = awsL[l0 + lane + k]; }
      const int f0 = wv * 8;
      for (int f = f0; f < f0 + 8; ++f) {
        const float* wc = Wconv + f * 62;
        float lf = 0.0f;
#pragma unroll
        for (int k = 0; k < 31; ++k) lf += awv[k] * wc[k] + awsv[k] * wc[31 + k];
        locL[lane * 33 + f] = lf;
      }
    }
    __syncthreads();
    {
      float locv[32];
#pragma unroll
      for (int f = 0; f < 32; ++f) locv[f] = locL[lane * 33 + f];
      float part = 0.0f;
      const int a0 = wv * 32;
      const float* pmp = pmT + (size_t)b * 128 * 256 + l0 + lane;
      for (int a = a0; a < a0 + 32; ++a) {
        float s = qL[a] + pmp[(size_t)a * 256];
        const float* wl = Wloc + a * 32;
#pragma unroll
        for (int f = 0; f < 32; ++f) s += locv[f] * wl[f];
        part += v[a] * tanhfast(s);
      }
      pr[wv * 64 + lane] = part;
    }
    __syncthreads();
    if (tid < 64) {
      float e = pr[tid] + pr[64 + tid] + pr[128 + tid] + pr[192 + tid];
      const int l = l0 + tid;
      if (l >= len[b]) e = -1e9f;
      eng[b * 256 + l] = e;
    }
  }
}

// ---------------------------------------------------------------------------
// k_ctx: 256 blocks = (b, enc-chunk of 128). softmax redundant per block.
// ---------------------------------------------------------------------------
__global__ __launch_bounds__(256) void k_ctx(
    const float* __restrict__ eng, const float* __restrict__ enc,
    const float* __restrict__ aws_i,
    float* __restrict__ ctx_o, float* __restrict__ aw_o, float* __restrict__ aws_o,
    float* __restrict__ out, int t)
{
  __shared__ float sm[896];
  const int tid = threadIdx.x;
  const int lane = tid & 63;
  const int wv = __builtin_amdgcn_readfirstlane(tid >> 6);
  const int b = blockIdx.x >> 2;
  const int ec = blockIdx.x & 3;
  const int e0 = ec * 128;
  float* eL = sm;            // 256
  float* wL = sm + 256;      // 256
  float* red = sm + 512;     // 8
  float* partL = sm + 640;   // 256

  eL[tid] = eng[b * 256 + tid];
  __syncthreads();
  float vv = eL[tid];
  for (int mm = 32; mm >= 1; mm >>= 1) vv = fmaxf(vv, __shfl_xor(vv, mm, 64));
  if (lane == 0) red[wv] = vv;
  __syncthreads();
  const float mx = fmaxf(fmaxf(red[0], red[1]), fmaxf(red[2], red[3]));
  const float pex = __expf(eL[tid] - mx);
  wL[tid] = pex;
  float ss = pex;
  for (int mm = 32; mm >= 1; mm >>= 1) ss += __shfl_xor(ss, mm, 64);
  if (lane == 0) red[4 + wv] = ss;
  __syncthreads();
  const float inv = 1.0f / (red[4] + red[5] + red[6] + red[7]);
  {
    const int e_i = tid & 127, lh = tid >> 7;
    float cp = 0.0f;
    const float* ep = enc + ((size_t)b * 256 + lh * 128) * 512 + e0 + e_i;
    for (int l = 0; l < 128; ++l) cp += wL[lh * 128 + l] * ep[(size_t)l * 512];
    partL[lh * 128 + e_i] = cp;
  }
  __syncthreads();
  if (tid < 128) ctx_o[(size_t)(e0 + tid) * 64 + b] = (partL[tid] + partL[128 + tid]) * inv;
  if (ec == 0) {
    const float w = wL[tid] * inv;
    aw_o[b * 256 + tid] = w;
    aws_o[b * 256 + tid] = aws_i[b * 256 + tid] + w;
    out[ALG_O + ((size_t)b * TB + t) * 256 + tid] = w;
  }
}

// ---------------------------------------------------------------------------
// k_dfin: dLSTM finish (ctx contribution) + pointwise + zoneout. 256 blocks.
// ---------------------------------------------------------------------------
__global__ __launch_bounds__(256) void k_dfin(
    const float* __restrict__ ctx_o, const float* __restrict__ gdT,
    const float* __restrict__ dh_i,  const float* __restrict__ dc_i,
    float* __restrict__ dh_o, float* __restrict__ dc_o,
    const float* __restrict__ dWih)
{
  __shared__ float sm[2048];
  const int tid = threadIdx.x;
  const int lane = tid & 63;
  const int wv = __builtin_amdgcn_readfirstlane(tid >> 6);
  const int u0 = blockIdx.x * 2;
  int rows[8];
#pragma unroll
  for (int j = 0; j < 8; ++j) rows[j] = u0 + (j >> 2) + 512 * (j & 3);
  float acc[8] = {};
  const int ks = wv * 128, ke = ks + 128;         // K = 512 (ctx2)
  gseg<8>(acc, ctx_o, dWih, 1024, 512, rows, 0, 512, ks, ke, lane);
#pragma unroll
  for (int j = 0; j < 8; ++j) sm[(wv * 8 + j) * 64 + lane] = acc[j];
  __syncthreads();
  if (tid < 128) {
    const int m = tid & 63, uq = tid >> 6;
    const int u = u0 + uq;
    float g[4];
#pragma unroll
    for (int q = 0; q < 4; ++q) {
      const int j = uq * 4 + q;
      const int row = u + 512 * q;
      g[q] = sm[j * 64 + m] + sm[(8 + j) * 64 + m] + sm[(16 + j) * 64 + m] + sm[(24 + j) * 64 + m]
           + gdT[(size_t)row * 64 + m];
    }
    const float co = dc_i[u * 64 + m], ho = dh_i[u * 64 + m];
    const float c2 = sigf(g[1]) * co + sigf(g[0]) * tanhfast(g[2]);
    const float h2 = sigf(g[3]) * tanhfast(c2);
    dh_o[u * 64 + m] = 0.1f * ho + 0.9f * h2;
    dc_o[u * 64 + m] = 0.1f * co + 0.9f * c2;
  }
}

// ---------------------------------------------------------------------------
extern "C" void kernel_launch(void* const* d_in, const int* in_sizes, int n_in,
                              void* d_out, int out_size, void* d_ws, size_t ws_size,
                              hipStream_t stream)
{
  (void)in_sizes; (void)n_in; (void)out_size;
  const float* enc   = (const float*)d_in[0];
  const int*   len   = (const int*)  d_in[1];
  const float* mels  = (const float*)d_in[2];
  const float* Wp1   = (const float*)d_in[3];
  const float* Wp2   = (const float*)d_in[4];
  const float* Wp3   = (const float*)d_in[5];
  const float* aWih  = (const float*)d_in[6];
  const float* aWhh  = (const float*)d_in[7];
  const float* abih  = (const float*)d_in[8];
  const float* abhh  = (const float*)d_in[9];
  const float* dWih  = (const float*)d_in[10];
  const float* dWhh  = (const float*)d_in[11];
  const float* dbih  = (const float*)d_in[12];
  const float* dbhh  = (const float*)d_in[13];
  const float* Wq    = (const float*)d_in[14];
  const float* Wm    = (const float*)d_in[15];
  const float* Wconv = (const float*)d_in[16];
  const float* Wloc  = (const float*)d_in[17];
  const float* vv    = (const float*)d_in[18];
  const float* Wout  = (const float*)d_in[19];
  const float* bout  = (const float*)d_in[20];
  const float* Wgate = (const float*)d_in[21];
  const float* bgate = (const float*)d_in[22];

  float* ws  = (float*)d_ws;
  float* out = (float*)d_out;

  // choose prenet chunking by available scratch
  const size_t need_big = (XB_O + (size_t)TB * 16384) * 4;   // ~63.3 MB
  const int CH = (ws_size >= need_big) ? TB : 64;

  init_kernel<<<256, 256, 0, stream>>>(Wq, ws);
  pm_kernel<<<256, 256, 0, stream>>>(enc, Wm, ws + PMT_O);

  for (int t = 0; t <= TB; ++t) {
    if (t < TB && (t % CH) == 0) {
      const int nt = (TB - t) < CH ? (TB - t) : CH;
      prenet_kernel<<<nt, 256, 0, stream>>>(mels, Wp1, Wp2, Wp3, ws + XB_O, t);
    }
    const int cur = t & 1;
    const float* xt = ws + XB_O + (size_t)(t % CH) * 16384;
    float* ah_i = ws + AH_O  + (size_t)cur * 32768;  float* ah_o = ws + AH_O  + (size_t)(cur ^ 1) * 32768;
    float* ac_i = ws + AC_O  + (size_t)cur * 32768;  float* ac_o = ws + AC_O  + (size_t)(cur ^ 1) * 32768;
    float* dh_i = ws + DH_O  + (size_t)cur * 32768;  float* dh_o = ws + DH_O  + (size_t)(cur ^ 1) * 32768;
    float* dc_i = ws + DC_O  + (size_t)cur * 32768;  float* dc_o = ws + DC_O  + (size_t)(cur ^ 1) * 32768;
    float* ctx_i = ws + CTX_O + (size_t)cur * 32768; float* ctx_o = ws + CTX_O + (size_t)(cur ^ 1) * 32768;
    float* aw_i = ws + AW_O  + (size_t)cur * 16384;  float* aw_o = ws + AW_O  + (size_t)(cur ^ 1) * 16384;
    float* aws_i = ws + AWS_O + (size_t)cur * 16384; float* aws_o = ws + AWS_O + (size_t)(cur ^ 1) * 16384;

    k_alstm<<<277, 256, 0, stream>>>(xt, ctx_i, ah_i, ac_i, ah_o, ac_o, dh_i,
                                     aWih, aWhh, abih, abhh,
                                     Wout, bout, Wgate, bgate,
                                     out, t, (t < TB) ? 1 : 0, (t > 0) ? 1 : 0);
    if (t == TB) break;
    k_energy<<<512, 256, 0, stream>>>(ah_o, dh_i, aw_i, aws_i,
                                      ws + PMT_O, ws + WQT_O, ws + GDT_O, ws + ENG_O,
                                      dWih, dWhh, dbih, dbhh, Wconv, Wloc, vv, len);
    k_ctx<<<256, 256, 0, stream>>>(ws + ENG_O, enc, aws_i, ctx_o, aw_o, aws_o, out, t);
    k_dfin<<<256, 256, 0, stream>>>(ctx_o, ws + GDT_O, dh_i, dc_i, dh_o, dc_o, dWih);
  }
}